// Round 4
// baseline (47.664 us; speedup 1.0000x reference)
//
#include <hip/hip_runtime.h>

// BilateralSlicer: grid (2,12,8,16,16) f32, guidance (2,1,1080,1920) f32
// out (2,12,1080,1920) f32.
#define BB 2
#define CC 12
#define DD 8
#define HG 16
#define WG 16
#define HH 1080
#define WH 1920
#define HWPIX (HH*WH)
// LDS layout: Gy[z][x][c], z-stride padded to 196 words (16*12+4) so that
// z*196 mod 32 = z*4 -> each z maps to a distinct 4-bank group.
#define ZSTR 196

// native vector type for nontemporal builtins (HIP float4 is a class -> rejected)
typedef float v4f __attribute__((ext_vector_type(4)));

__global__ __launch_bounds__(512) void slice_row_kernel(
        const float* __restrict__ g, const float* __restrict__ guid,
        float* __restrict__ out) {
    const int bid = blockIdx.x;
    const int b   = bid / HH;
    const int y   = bid - b*HH;      // output row
    const int t   = threadIdx.x;

    __shared__ __attribute__((aligned(16))) float gy[DD*ZSTR]; // 6272 B

    // ---- per-row y interpolation params (wave-uniform) ----
    float sy = fmaxf((y + 0.5f) * (16.0f/1080.0f) - 0.5f, 0.0f);
    int y0 = min((int)sy, HG-1);     // sy>=0 so trunc==floor
    int y1 = min(y0 + 1, HG-1);
    float wy = sy - (float)y0;

    // ---- stage y-interpolated grid slab into LDS (one pass, 384 threads) ----
    // entry e = (c*DD + z)*4 + x4 ; x-contiguous float4 loads from original layout
    if (t < CC*DD*4) {
        int x4 = t & 3;
        int zz = (t >> 2) & 7;
        int c  = t >> 5;
        const float* gc = g + (size_t)b*(CC*DD*HG*WG) + ((size_t)c*DD + zz)*(HG*WG);
        float4 v0 = *(const float4*)(gc + y0*WG + x4*4);
        float4 v1 = *(const float4*)(gc + y1*WG + x4*4);
        float4 rv;
        rv.x = (1.0f-wy)*v0.x + wy*v1.x;
        rv.y = (1.0f-wy)*v0.y + wy*v1.y;
        rv.z = (1.0f-wy)*v0.z + wy*v1.z;
        rv.w = (1.0f-wy)*v0.w + wy*v1.w;
        int base = zz*ZSTR + (x4*4)*12 + c;   // scatter 4 x-values for channel c
        gy[base     ] = rv.x;
        gy[base + 12] = rv.y;
        gy[base + 24] = rv.z;
        gy[base + 36] = rv.w;
    }
    __syncthreads();

    if (t >= 480) return;            // 480 threads * 4 px = 1920 px per block

    const int xq = t*4;              // first x of this thread's pixel quad
    const v4f gq = __builtin_nontemporal_load(
        (const v4f*)(guid + (size_t)b*HWPIX + (size_t)y*WH + xq));

    float acc[4][12];

    #pragma unroll
    for (int k = 0; k < 4; ++k) {
        float gv = gq[k];
        float bf = gv * (float)(DD-1);
        int zlo = min(max((int)floorf(bf), 0), DD-1);
        int zhi = min(zlo + 1, DD-1);
        float wz = bf - (float)zlo;

        int px = xq + k;
        float sx = fmaxf((px + 0.5f) * (16.0f/1920.0f) - 0.5f, 0.0f);
        int x0 = min((int)sx, WG-1);
        int x1 = min(x0 + 1, WG-1);
        float wx = sx - (float)x0;

        float w00 = (1.0f-wz)*(1.0f-wx);
        float w01 = (1.0f-wz)*wx;
        float w10 = wz*(1.0f-wx);
        float w11 = wz*wx;

        const float* plo = &gy[zlo*ZSTR];
        const float* phi = &gy[zhi*ZSTR];

        #pragma unroll
        for (int c4 = 0; c4 < 3; ++c4) {
            float4 v00 = *(const float4*)(plo + x0*12 + c4*4);
            float4 v01 = *(const float4*)(plo + x1*12 + c4*4);
            float4 v10 = *(const float4*)(phi + x0*12 + c4*4);
            float4 v11 = *(const float4*)(phi + x1*12 + c4*4);
            acc[k][c4*4+0] = w00*v00.x + w01*v01.x + w10*v10.x + w11*v11.x;
            acc[k][c4*4+1] = w00*v00.y + w01*v01.y + w10*v10.y + w11*v11.y;
            acc[k][c4*4+2] = w00*v00.z + w01*v01.z + w10*v10.z + w11*v11.z;
            acc[k][c4*4+3] = w00*v00.w + w01*v01.w + w10*v10.w + w11*v11.w;
        }
    }

    // ---- 12 coalesced nontemporal float4 stores (4 px per channel) ----
    float* ob = out + (size_t)b*(CC*HWPIX) + (size_t)y*WH + xq;
    #pragma unroll
    for (int c = 0; c < CC; ++c) {
        v4f v = { acc[0][c], acc[1][c], acc[2][c], acc[3][c] };
        __builtin_nontemporal_store(v, (v4f*)(ob + (size_t)c*HWPIX));
    }
}

extern "C" void kernel_launch(void* const* d_in, const int* in_sizes, int n_in,
                              void* d_out, int out_size, void* d_ws, size_t ws_size,
                              hipStream_t stream) {
    const float* grid = (const float*)d_in[0];
    const float* guid = (const float*)d_in[1];
    float* out = (float*)d_out;

    const int nblk = BB * HH;        // 2160 blocks: one per (batch, row)
    slice_row_kernel<<<nblk, 512, 0, stream>>>(grid, guid, out);
}

// Round 5
// 44.730 us; speedup vs baseline: 1.0656x; 1.0656x over previous
//
#include <hip/hip_runtime.h>

// BilateralSlicer: grid (2,12,8,16,16) f32, guidance (2,1,1080,1920) f32
// out (2,12,1080,1920) f32.
#define BB 2
#define CC 12
#define DD 8
#define HG 16
#define WG 16
#define HH 1080
#define WH 1920
#define HWPIX (HH*WH)
// LDS layout: Gy[z][x][c], z-stride padded to 196 words (16*12+4) so that
// z*196 mod 32 = z*4 -> each z maps to a distinct 4-bank group.
#define ZSTR 196

// native vector type for nontemporal builtins (HIP float4 is a class -> rejected)
typedef float v4f __attribute__((ext_vector_type(4)));

__global__ __launch_bounds__(256) void slice_row_kernel(
        const float* __restrict__ g, const float* __restrict__ guid,
        float* __restrict__ out) {
    const int bid = blockIdx.x;
    const int b   = bid / (HH*2);
    const int r   = bid - b*(HH*2);
    const int y   = r >> 1;          // output row
    const int s   = r & 1;           // half-row segment (0: px 0..959, 1: 960..1919)
    const int t   = threadIdx.x;

    __shared__ __attribute__((aligned(16))) float gy[DD*ZSTR]; // 6272 B

    // ---- per-row y interpolation params (wave-uniform) ----
    float sy = fmaxf((y + 0.5f) * (16.0f/1080.0f) - 0.5f, 0.0f);
    int y0 = min((int)sy, HG-1);     // sy>=0 so trunc==floor
    int y1 = min(y0 + 1, HG-1);
    float wy = sy - (float)y0;

    // ---- stage y-interpolated grid slab into LDS ----
    // entries e = (c*DD + z)*4 + x4 ; x-contiguous float4 loads from original layout
    const float* gb = g + (size_t)b * (CC*DD*HG*WG);
    for (int e = t; e < CC*DD*4; e += 256) {
        int x4 = e & 3;
        int zz = (e >> 2) & 7;
        int c  = e >> 5;
        const float* gc = gb + ((size_t)c*DD + zz)*(HG*WG);
        float4 v0 = *(const float4*)(gc + y0*WG + x4*4);
        float4 v1 = *(const float4*)(gc + y1*WG + x4*4);
        float4 rv;
        rv.x = (1.0f-wy)*v0.x + wy*v1.x;
        rv.y = (1.0f-wy)*v0.y + wy*v1.y;
        rv.z = (1.0f-wy)*v0.z + wy*v1.z;
        rv.w = (1.0f-wy)*v0.w + wy*v1.w;
        int base = zz*ZSTR + (x4*4)*12 + c;   // scatter 4 x-values for channel c
        gy[base     ] = rv.x;
        gy[base + 12] = rv.y;
        gy[base + 24] = rv.z;
        gy[base + 36] = rv.w;
    }
    __syncthreads();

    if (t >= 240) return;            // 240 threads * 4 px = 960 px per block

    const int xq = s*960 + t*4;      // first x of this thread's pixel quad
    const float4 gq = *(const float4*)(guid + (size_t)b*HWPIX + (size_t)y*WH + xq);

    float acc[4][12];

    #pragma unroll
    for (int k = 0; k < 4; ++k) {
        float gv = (k==0) ? gq.x : (k==1) ? gq.y : (k==2) ? gq.z : gq.w;
        float bf = gv * (float)(DD-1);
        int zlo = min(max((int)floorf(bf), 0), DD-1);
        int zhi = min(zlo + 1, DD-1);
        float wz = bf - (float)zlo;

        int px = xq + k;
        float sx = fmaxf((px + 0.5f) * (16.0f/1920.0f) - 0.5f, 0.0f);
        int x0 = min((int)sx, WG-1);
        int x1 = min(x0 + 1, WG-1);
        float wx = sx - (float)x0;

        float w00 = (1.0f-wz)*(1.0f-wx);
        float w01 = (1.0f-wz)*wx;
        float w10 = wz*(1.0f-wx);
        float w11 = wz*wx;

        const float* plo = &gy[zlo*ZSTR];
        const float* phi = &gy[zhi*ZSTR];

        #pragma unroll
        for (int c4 = 0; c4 < 3; ++c4) {
            float4 v00 = *(const float4*)(plo + x0*12 + c4*4);
            float4 v01 = *(const float4*)(plo + x1*12 + c4*4);
            float4 v10 = *(const float4*)(phi + x0*12 + c4*4);
            float4 v11 = *(const float4*)(phi + x1*12 + c4*4);
            acc[k][c4*4+0] = w00*v00.x + w01*v01.x + w10*v10.x + w11*v11.x;
            acc[k][c4*4+1] = w00*v00.y + w01*v01.y + w10*v10.y + w11*v11.y;
            acc[k][c4*4+2] = w00*v00.z + w01*v01.z + w10*v10.z + w11*v11.z;
            acc[k][c4*4+3] = w00*v00.w + w01*v01.w + w10*v10.w + w11*v11.w;
        }
    }

    // ---- 12 coalesced NONTEMPORAL float4 stores (4 px per channel) ----
    float* ob = out + (size_t)b*(CC*HWPIX) + (size_t)y*WH + xq;
    #pragma unroll
    for (int c = 0; c < CC; ++c) {
        v4f v = { acc[0][c], acc[1][c], acc[2][c], acc[3][c] };
        __builtin_nontemporal_store(v, (v4f*)(ob + (size_t)c*HWPIX));
    }
}

extern "C" void kernel_launch(void* const* d_in, const int* in_sizes, int n_in,
                              void* d_out, int out_size, void* d_ws, size_t ws_size,
                              hipStream_t stream) {
    const float* grid = (const float*)d_in[0];
    const float* guid = (const float*)d_in[1];
    float* out = (float*)d_out;

    const int nblk = BB * HH * 2;    // 4320 blocks: (batch, row, half-row)
    slice_row_kernel<<<nblk, 256, 0, stream>>>(grid, guid, out);
}

// Round 6
// 38.206 us; speedup vs baseline: 1.2476x; 1.1708x over previous
//
#include <hip/hip_runtime.h>

// BilateralSlicer: grid (2,12,8,16,16) f32, guidance (2,1,1080,1920) f32
// out (2,12,1080,1920) f32.
// Structure: one block per (batch, row, half-row); per-row y-interpolated
// grid slab staged in LDS (channel-last), 4 px/thread gather + coalesced
// float4 stores. NT stores tested (r4/r5): -17% — reverted. 512-thr blocks
// tested (r4): -8% — reverted.
#define BB 2
#define CC 12
#define DD 8
#define HG 16
#define WG 16
#define HH 1080
#define WH 1920
#define HWPIX (HH*WH)
// LDS layout: Gy[z][x][c], z-stride padded to 196 words (16*12+4) so that
// z*196 mod 32 = z*4 -> each z maps to a distinct 4-bank group.
#define ZSTR 196

__global__ __launch_bounds__(256) void slice_row_kernel(
        const float* __restrict__ g, const float* __restrict__ guid,
        float* __restrict__ out) {
    const int bid = blockIdx.x;
    const int b   = bid / (HH*2);
    const int r   = bid - b*(HH*2);
    const int y   = r >> 1;          // output row
    const int s   = r & 1;           // half-row segment (0: px 0..959, 1: 960..1919)
    const int t   = threadIdx.x;

    __shared__ __attribute__((aligned(16))) float gy[DD*ZSTR]; // 6272 B

    // ---- per-row y interpolation params (wave-uniform) ----
    float sy = fmaxf((y + 0.5f) * (16.0f/1080.0f) - 0.5f, 0.0f);
    int y0 = min((int)sy, HG-1);     // sy>=0 so trunc==floor
    int y1 = min(y0 + 1, HG-1);
    float wy = sy - (float)y0;

    // ---- stage y-interpolated grid slab into LDS ----
    // entries e = (c*DD + z)*4 + x4 ; x-contiguous float4 loads from original layout
    const float* gb = g + (size_t)b * (CC*DD*HG*WG);
    for (int e = t; e < CC*DD*4; e += 256) {
        int x4 = e & 3;
        int zz = (e >> 2) & 7;
        int c  = e >> 5;
        const float* gc = gb + ((size_t)c*DD + zz)*(HG*WG);
        float4 v0 = *(const float4*)(gc + y0*WG + x4*4);
        float4 v1 = *(const float4*)(gc + y1*WG + x4*4);
        float4 rv;
        rv.x = (1.0f-wy)*v0.x + wy*v1.x;
        rv.y = (1.0f-wy)*v0.y + wy*v1.y;
        rv.z = (1.0f-wy)*v0.z + wy*v1.z;
        rv.w = (1.0f-wy)*v0.w + wy*v1.w;
        int base = zz*ZSTR + (x4*4)*12 + c;   // scatter 4 x-values for channel c
        gy[base     ] = rv.x;
        gy[base + 12] = rv.y;
        gy[base + 24] = rv.z;
        gy[base + 36] = rv.w;
    }
    __syncthreads();

    if (t >= 240) return;            // 240 threads * 4 px = 960 px per block

    const int xq = s*960 + t*4;      // first x of this thread's pixel quad
    const float4 gq = *(const float4*)(guid + (size_t)b*HWPIX + (size_t)y*WH + xq);

    float acc[4][12];

    #pragma unroll
    for (int k = 0; k < 4; ++k) {
        float gv = (k==0) ? gq.x : (k==1) ? gq.y : (k==2) ? gq.z : gq.w;
        float bf = gv * (float)(DD-1);
        int zlo = min(max((int)floorf(bf), 0), DD-1);
        int zhi = min(zlo + 1, DD-1);
        float wz = bf - (float)zlo;

        int px = xq + k;
        float sx = fmaxf((px + 0.5f) * (16.0f/1920.0f) - 0.5f, 0.0f);
        int x0 = min((int)sx, WG-1);
        int x1 = min(x0 + 1, WG-1);
        float wx = sx - (float)x0;

        float w00 = (1.0f-wz)*(1.0f-wx);
        float w01 = (1.0f-wz)*wx;
        float w10 = wz*(1.0f-wx);
        float w11 = wz*wx;

        const float* plo = &gy[zlo*ZSTR];
        const float* phi = &gy[zhi*ZSTR];

        #pragma unroll
        for (int c4 = 0; c4 < 3; ++c4) {
            float4 v00 = *(const float4*)(plo + x0*12 + c4*4);
            float4 v01 = *(const float4*)(plo + x1*12 + c4*4);
            float4 v10 = *(const float4*)(phi + x0*12 + c4*4);
            float4 v11 = *(const float4*)(phi + x1*12 + c4*4);
            acc[k][c4*4+0] = w00*v00.x + w01*v01.x + w10*v10.x + w11*v11.x;
            acc[k][c4*4+1] = w00*v00.y + w01*v01.y + w10*v10.y + w11*v11.y;
            acc[k][c4*4+2] = w00*v00.z + w01*v01.z + w10*v10.z + w11*v11.z;
            acc[k][c4*4+3] = w00*v00.w + w01*v01.w + w10*v10.w + w11*v11.w;
        }
    }

    // ---- 12 coalesced float4 stores (4 px per channel) ----
    float* ob = out + (size_t)b*(CC*HWPIX) + (size_t)y*WH + xq;
    #pragma unroll
    for (int c = 0; c < CC; ++c) {
        float4 v = make_float4(acc[0][c], acc[1][c], acc[2][c], acc[3][c]);
        *(float4*)(ob + (size_t)c*HWPIX) = v;
    }
}

extern "C" void kernel_launch(void* const* d_in, const int* in_sizes, int n_in,
                              void* d_out, int out_size, void* d_ws, size_t ws_size,
                              hipStream_t stream) {
    const float* grid = (const float*)d_in[0];
    const float* guid = (const float*)d_in[1];
    float* out = (float*)d_out;

    const int nblk = BB * HH * 2;    // 4320 blocks: (batch, row, half-row)
    slice_row_kernel<<<nblk, 256, 0, stream>>>(grid, guid, out);
}